// Round 11
// baseline (35.275 us; speedup 1.0000x reference)
//
#include <hip/hip_runtime.h>
#include <hip/hip_bf16.h>

#define B_ 8
#define N_ 64
#define T_ 512
#define D_ 128
#define H_ 7

typedef __attribute__((ext_vector_type(8))) short short8;   // 8 bf16 (MFMA A/B frag)
typedef __attribute__((ext_vector_type(4))) float f32x4;    // MFMA C/D frag
typedef __attribute__((ext_vector_type(4))) int   iv4;

union BF2 { __hip_bfloat162 h2; unsigned u; };
__device__ __forceinline__ unsigned pk2(float a, float b) {  // v_cvt_pk_bf16_f32 (RNE)
    BF2 r; r.h2 = __float22bfloat162_rn(make_float2(a, b)); return r.u;
}
__device__ __forceinline__ short8 cvt8(const float4& a, const float4& b) {
    iv4 v = { (int)pk2(a.x, a.y), (int)pk2(a.z, a.w),
              (int)pk2(b.x, b.y), (int)pk2(b.z, b.w) };
    return __builtin_bit_cast(short8, v);
}

// Persistent 2-tile blocks: grid 2048, block handles (b, t0) and (b, t0+1).
// Tile i+1's global loads issue BEFORE tile i's first barrier -> HBM stream
// stays busy through tile i's compute. Q fragments hoisted (tile-invariant).
// Max-free softmax (logits ~ N(0,1)); per-h 1/Z applied post-PV.
// Frag layouts (m89-verified): A row=l&15,k=(l>>4)*8+j; B col=l&15,k same;
// C/D col=l&15, row=(l>>4)*4+reg.
__global__ __launch_bounds__(256, 6)
void MultiHeadPool_45226005627089_kernel(const float* __restrict__ others,
                                         const float* __restrict__ queries,
                                         float* __restrict__ out) {
    __shared__ __align__(16) ushort XL[N_ * 136];   // bf16 X, row pad 136, d-swizzled: 17408 B
    __shared__ __align__(16) ushort WL[16 * 72];    // bf16 unnormalized e[h][n], pad 72: 2304 B
    __shared__ __align__(16) float  SM[16 * 4];     // per-(h,wave) partial sum: 256 B

    const int tid = threadIdx.x;
    const int w   = tid >> 6;        // wave 0..3
    const int l   = tid & 63;
    const int c   = l & 15;
    const int p   = l >> 4;

    const int blk = blockIdx.x;          // 2048 blocks; tiles 2blk, 2blk+1
    const int b   = blk >> 8;            // 256 blocks per batch
    const int t0  = (blk & 255) * 2;

    const int    n    = 16 * w + c;
    const int    swn  = ((n >> 3) & 3) << 4;        // d-chunk XOR swizzle for XL
    const float* xrow = others + ((size_t)b * N_ * T_ + t0) * D_
                               + (size_t)n * (T_ * D_) + 8 * p;
    float* obt = out + ((size_t)(b * T_ + t0)) * (H_ * D_);

    // ---- Q fragments (B-operand), hoisted: col = h = c (clamped; masked at store) ----
    // k-index = 32s + 8p + j  (the 8p term was the R10 bug)
    short8 qb[4];
    {
        const float* qrow = queries + (c < H_ ? c : 0) * D_;
        #pragma unroll
        for (int s = 0; s < 4; ++s) {
            const float4 a  = *(const float4*)(qrow + 32 * s + 8 * p);
            const float4 bq = *(const float4*)(qrow + 32 * s + 8 * p + 4);
            qb[s] = cvt8(a, bq);
        }
    }

    // ---- prefetch tile 0 (d = 32s + 8p + j) ----
    float4 pre[8];
    #pragma unroll
    for (int s = 0; s < 4; ++s) {
        pre[2 * s]     = *(const float4*)(xrow + 32 * s);
        pre[2 * s + 1] = *(const float4*)(xrow + 32 * s + 4);
    }

    for (int it = 0; it < 2; ++it) {
        // ---- cvt & stage to XL (swizzled) ----
        short8 xb[4];
        #pragma unroll
        for (int s = 0; s < 4; ++s) {
            xb[s] = cvt8(pre[2 * s], pre[2 * s + 1]);
            const int d0 = (32 * s + 8 * p) ^ swn;
            *(short8*)&XL[n * 136 + d0] = xb[s];
        }

        // ---- fire-and-forget prefetch of tile 1 (lands during this tile's compute) ----
        if (it == 0) {
            #pragma unroll
            for (int s = 0; s < 4; ++s) {
                pre[2 * s]     = *(const float4*)(xrow + D_ + 32 * s);
                pre[2 * s + 1] = *(const float4*)(xrow + D_ + 32 * s + 4);
            }
        }

        // ---- QK^T: lane holds P[n-in-tile = 4p+r][h = c] ----
        f32x4 c1 = {0.f, 0.f, 0.f, 0.f};
        #pragma unroll
        for (int s = 0; s < 4; ++s)
            c1 = __builtin_amdgcn_mfma_f32_16x16x32_bf16(xb[s], qb[s], c1, 0, 0, 0);

        const float scale = 0.0883883476483184f;  // 128^-0.5
        float e[4];
        #pragma unroll
        for (int r = 0; r < 4; ++r) e[r] = __expf(c1[r] * scale);   // max-free
        float s_w = e[0] + e[1] + e[2] + e[3];
        s_w += __shfl_xor(s_w, 16);       // reduce over p (same h = c)
        s_w += __shfl_xor(s_w, 32);
        if (l < 16) SM[c * 4 + w] = s_w;
        {
            const unsigned w01 = pk2(e[0], e[1]);
            const unsigned w23 = pk2(e[2], e[3]);
            *(uint2*)&WL[c * 72 + 16 * w + 4 * p] = make_uint2(w01, w23);
        }
        __syncthreads();   // XL + WL + SM ready

        // ---- PV: A2 = E (row=h=c, k=n); B2 = X^T gather from swizzled XL ----
        short8 a2[2];
        #pragma unroll
        for (int ks = 0; ks < 2; ++ks)
            a2[ks] = *(const short8*)&WL[c * 72 + 32 * ks + 8 * p];

        f32x4 o2[2];
        #pragma unroll
        for (int dti = 0; dti < 2; ++dti) {
            const int dt = 2 * w + dti;           // d-tile: cols [16dt, 16dt+16)
            f32x4 acc = {0.f, 0.f, 0.f, 0.f};
            #pragma unroll
            for (int ks = 0; ks < 2; ++ks) {
                // element (n = 32ks+8p+jj, d = 16dt+c); writer swizzle term = p<<4
                const int base = (32 * ks + 8 * p) * 136 + ((16 * dt + c) ^ (p << 4));
                short8 bf;
                #pragma unroll
                for (int jj = 0; jj < 8; ++jj)
                    bf[jj] = (short)XL[base + 136 * jj];
                acc = __builtin_amdgcn_mfma_f32_16x16x32_bf16(a2[ks], bf, acc, 0, 0, 0);
            }
            o2[dti] = acc;
        }

        // ---- per-h normalization: Z_h = sum over waves; lane covers h = 4p + r ----
        float rz[4];
        #pragma unroll
        for (int r = 0; r < 4; ++r) {
            const int h = 4 * p + r;
            const float4 z4 = *(const float4*)&SM[h * 4];
            rz[r] = 1.0f / (z4.x + z4.y + z4.z + z4.w);
        }

        // ---- store: lane holds O[h = 4p + r][d = 16*(2w+dti) + c] ----
        #pragma unroll
        for (int dti = 0; dti < 2; ++dti) {
            const int d = 16 * (2 * w + dti) + c;
            #pragma unroll
            for (int r = 0; r < 4; ++r) {
                const int h = 4 * p + r;
                if (h < H_)
                    obt[(size_t)it * (H_ * D_) + h * D_ + d] = o2[dti][r] * rz[r];
            }
        }
        __syncthreads();   // XL/WL/SM free for next tile
    }
}

extern "C" void kernel_launch(void* const* d_in, const int* in_sizes, int n_in,
                              void* d_out, int out_size, void* d_ws, size_t ws_size,
                              hipStream_t stream) {
    // d_in[0] = ego (B,T,D) -- unused by the reference computation
    const float* others  = (const float*)d_in[1];   // (B,N,T,D) f32
    const float* queries = (const float*)d_in[2];   // (H,D) f32
    float* out = (float*)d_out;                     // (B,T,H,D) f32

    dim3 grid(B_ * T_ / 2);
    dim3 block(256);
    MultiHeadPool_45226005627089_kernel<<<grid, block, 0, stream>>>(others, queries, out);
}

// Round 12
// 32.554 us; speedup vs baseline: 1.0836x; 1.0836x over previous
//
#include <hip/hip_runtime.h>
#include <hip/hip_bf16.h>

#define B_ 8
#define N_ 64
#define T_ 512
#define D_ 128
#define H_ 7

typedef __attribute__((ext_vector_type(8))) short short8;   // 8 bf16 (MFMA A/B frag)
typedef __attribute__((ext_vector_type(4))) float f32x4;    // MFMA C/D frag
typedef __attribute__((ext_vector_type(4))) int   iv4;

union BF2 { __hip_bfloat162 h2; unsigned u; };
__device__ __forceinline__ unsigned pk2(float a, float b) {  // v_cvt_pk_bf16_f32 (RNE)
    BF2 r; r.h2 = __float22bfloat162_rn(make_float2(a, b)); return r.u;
}
__device__ __forceinline__ short8 cvt8(const float4& a, const float4& b) {
    iv4 v = { (int)pk2(a.x, a.y), (int)pk2(a.z, a.w),
              (int)pk2(b.x, b.y), (int)pk2(b.z, b.w) };
    return __builtin_bit_cast(short8, v);
}

// R9 structure (best: 32.6 us) + chunked XCD swizzle (the ONLY change):
// blocks 512*x .. 512*x+511 land on XCD x -> each XCD streams one batch b
// sequentially (DRAM/fabric page locality test).
// One block per (b,t); 8 blocks/CU (LDS 19968 B). ONE barrier.
// Max-free softmax (logits ~ N(0,1)); per-h 1/Z applied post-PV.
// Frag layouts (m89-verified): A row=l&15,k=(l>>4)*8+j; B col=l&15,k same;
// C/D col=l&15, row=(l>>4)*4+reg.
__global__ __launch_bounds__(256, 8)
void MultiHeadPool_45226005627089_kernel(const float* __restrict__ others,
                                         const float* __restrict__ queries,
                                         float* __restrict__ out) {
    __shared__ __align__(16) ushort XL[N_ * 136];   // bf16 X, row pad 136, d-swizzled: 17408 B
    __shared__ __align__(16) ushort WL[16 * 72];    // bf16 unnormalized e[h][n], pad 72: 2304 B
    __shared__ __align__(16) float  SM[16 * 4];     // per-(h,wave) partial sum: 256 B

    const int tid = threadIdx.x;
    const int w   = tid >> 6;        // wave 0..3
    const int l   = tid & 63;
    const int c   = l & 15;
    const int p   = l >> 4;

    // chunked XCD swizzle: bijective since 4096 % 8 == 0 (cpx = 512)
    const int bt = ((blockIdx.x & 7) << 9) | (blockIdx.x >> 3);   // = b*T + t
    const int b  = bt >> 9;
    const int t  = bt & (T_ - 1);

    const float* obase = others + ((size_t)b * N_ * T_ + t) * D_;   // + n*T*D + d
    const int    n     = 16 * w + c;
    const float* xrow  = obase + (size_t)n * (T_ * D_);
    const int    swn   = ((n >> 3) & 3) << 4;       // d-chunk XOR swizzle for XL

    // ---- X load in A-frag layout (d = 32s+8p+j), convert early ----
    short8 xb[4];
    {
        float4 t0 = *(const float4*)(xrow + 8 * p);
        float4 t1 = *(const float4*)(xrow + 8 * p + 4);
        float4 t2 = *(const float4*)(xrow + 32 + 8 * p);
        float4 t3 = *(const float4*)(xrow + 32 + 8 * p + 4);
        xb[0] = cvt8(t0, t1);
        xb[1] = cvt8(t2, t3);
        t0 = *(const float4*)(xrow + 64 + 8 * p);
        t1 = *(const float4*)(xrow + 64 + 8 * p + 4);
        t2 = *(const float4*)(xrow + 96 + 8 * p);
        t3 = *(const float4*)(xrow + 96 + 8 * p + 4);
        xb[2] = cvt8(t0, t1);
        xb[3] = cvt8(t2, t3);
    }
    // stage to XL (swizzled)
    #pragma unroll
    for (int s = 0; s < 4; ++s) {
        const int d0 = (32 * s + 8 * p) ^ swn;
        *(short8*)&XL[n * 136 + d0] = xb[s];
    }

    // ---- Q fragments (B-operand): col = h = c; clamp c>=7 to row 0 (masked later) ----
    short8 qb[4];
    {
        const float* qrow = queries + (c < H_ ? c : 0) * D_;
        #pragma unroll
        for (int s = 0; s < 4; ++s) {
            const float4 a  = *(const float4*)(qrow + 32 * s + 8 * p);
            const float4 bq = *(const float4*)(qrow + 32 * s + 8 * p + 4);
            qb[s] = cvt8(a, bq);
        }
    }

    // ---- QK^T: lane holds P[n-in-tile = 4p+r][h = c] ----
    f32x4 c1 = {0.f, 0.f, 0.f, 0.f};
    #pragma unroll
    for (int s = 0; s < 4; ++s)
        c1 = __builtin_amdgcn_mfma_f32_16x16x32_bf16(xb[s], qb[s], c1, 0, 0, 0);

    const float scale = 0.0883883476483184f;  // 128^-0.5
    float e[4];
    #pragma unroll
    for (int r = 0; r < 4; ++r) e[r] = __expf(c1[r] * scale);   // max-free
    float s_w = e[0] + e[1] + e[2] + e[3];
    s_w += __shfl_xor(s_w, 16);       // reduce over p (same h = c)
    s_w += __shfl_xor(s_w, 32);
    if (l < 16) SM[c * 4 + w] = s_w;

    // unnormalized weights -> bf16 -> WL[h = c][n = 16w + 4p + r]
    {
        const unsigned w01 = pk2(e[0], e[1]);
        const unsigned w23 = pk2(e[2], e[3]);
        *(uint2*)&WL[c * 72 + 16 * w + 4 * p] = make_uint2(w01, w23);
    }
    __syncthreads();   // the ONLY barrier

    // ---- PV: A2 = E (row=h=c, k=n); B2 = X^T gather from swizzled XL ----
    short8 a2[2];
    #pragma unroll
    for (int ks = 0; ks < 2; ++ks)
        a2[ks] = *(const short8*)&WL[c * 72 + 32 * ks + 8 * p];

    f32x4 o2[2];
    #pragma unroll
    for (int dti = 0; dti < 2; ++dti) {
        const int dt = 2 * w + dti;               // d-tile: cols [16dt, 16dt+16)
        f32x4 acc = {0.f, 0.f, 0.f, 0.f};
        #pragma unroll
        for (int ks = 0; ks < 2; ++ks) {
            // element (n = 32ks+8p+jj, d = 16dt+c); writer swizzle term = p<<4
            const int base = (32 * ks + 8 * p) * 136 + ((16 * dt + c) ^ (p << 4));
            short8 bf;
            #pragma unroll
            for (int jj = 0; jj < 8; ++jj)
                bf[jj] = (short)XL[base + 136 * jj];
            acc = __builtin_amdgcn_mfma_f32_16x16x32_bf16(a2[ks], bf, acc, 0, 0, 0);
        }
        o2[dti] = acc;
    }

    // ---- per-h normalization: Z_h = sum over waves; lane covers h = 4p + r ----
    float rz[4];
    #pragma unroll
    for (int r = 0; r < 4; ++r) {
        const int h = 4 * p + r;
        const float4 z4 = *(const float4*)&SM[h * 4];   // broadcast within c-group
        rz[r] = 1.0f / (z4.x + z4.y + z4.z + z4.w);
    }

    // ---- store: lane holds O[h = 4p + r][d = 16*(2w+dti) + c] ----
    #pragma unroll
    for (int dti = 0; dti < 2; ++dti) {
        const int d = 16 * (2 * w + dti) + c;
        #pragma unroll
        for (int r = 0; r < 4; ++r) {
            const int h = 4 * p + r;
            if (h < H_)
                out[(size_t)bt * (H_ * D_) + h * D_ + d] = o2[dti][r] * rz[r];
        }
    }
}

extern "C" void kernel_launch(void* const* d_in, const int* in_sizes, int n_in,
                              void* d_out, int out_size, void* d_ws, size_t ws_size,
                              hipStream_t stream) {
    // d_in[0] = ego (B,T,D) -- unused by the reference computation
    const float* others  = (const float*)d_in[1];   // (B,N,T,D) f32
    const float* queries = (const float*)d_in[2];   // (H,D) f32
    float* out = (float*)d_out;                     // (B,T,H,D) f32

    dim3 grid(B_ * T_);
    dim3 block(256);
    MultiHeadPool_45226005627089_kernel<<<grid, block, 0, stream>>>(others, queries, out);
}

// Round 13
// 29.364 us; speedup vs baseline: 1.2013x; 1.1087x over previous
//
#include <hip/hip_runtime.h>
#include <hip/hip_bf16.h>

#define B_ 8
#define N_ 64
#define T_ 512
#define D_ 128
#define H_ 7

typedef __attribute__((ext_vector_type(8))) short short8;   // 8 bf16 (MFMA A/B frag)
typedef __attribute__((ext_vector_type(4))) float f32x4;    // MFMA C/D frag
typedef __attribute__((ext_vector_type(4))) int   iv4;

union BF2 { __hip_bfloat162 h2; unsigned u; };
__device__ __forceinline__ unsigned pk2(float a, float b) {  // v_cvt_pk_bf16_f32 (RNE)
    BF2 r; r.h2 = __float22bfloat162_rn(make_float2(a, b)); return r.u;
}
__device__ __forceinline__ short8 cvt8(const float4& a, const float4& b) {
    iv4 v = { (int)pk2(a.x, a.y), (int)pk2(a.z, a.w),
              (int)pk2(b.x, b.y), (int)pk2(b.z, b.w) };
    return __builtin_bit_cast(short8, v);
}

// Raw barrier that does NOT drain vmcnt: waits only on LDS ops, so global
// loads issued for the next tile stay in flight across it.
__device__ __forceinline__ void lds_barrier() {
    asm volatile("s_waitcnt lgkmcnt(0)" ::: "memory");
    asm volatile("s_barrier" ::: "memory");
}

// TPB=2 persistent blocks (grid 2048): tile t0 computes while tile t0+1's
// 16 dwordx4 loads are in flight (issued pre-barrier; barriers are lgkm-only).
// Max-free softmax (logits ~ N(0,1)); per-h 1/Z post-PV.
// Frag layouts (m89-verified): A row=l&15,k=(l>>4)*8+j; B col=l&15,k same;
// C/D col=l&15, row=(l>>4)*4+reg.
__global__ __launch_bounds__(256, 5)
void MultiHeadPool_45226005627089_kernel(const float* __restrict__ others,
                                         const float* __restrict__ queries,
                                         float* __restrict__ out) {
    __shared__ __align__(16) ushort XL[N_ * 136];   // bf16 X, row pad 136, d-swizzled
    __shared__ __align__(16) ushort WL[16 * 72];    // bf16 unnormalized e[h][n]
    __shared__ __align__(16) float  SM[16 * 4];     // per-(h,wave) partial sum

    const int tid = threadIdx.x;
    const int w   = tid >> 6;        // wave 0..3
    const int l   = tid & 63;
    const int c   = l & 15;
    const int p   = l >> 4;

    const int blk = blockIdx.x;          // 2048 blocks; tiles t0, t0+1
    const int b   = blk >> 8;
    const int t0  = (blk & 255) * 2;

    const int    n    = 16 * w + c;
    const int    swn  = ((n >> 3) & 3) << 4;        // d-chunk XOR swizzle for XL
    const float* xrow = others + ((size_t)b * N_ * T_ + t0) * D_
                               + (size_t)n * (T_ * D_) + 8 * p;
    float* obt = out + ((size_t)(b * T_ + t0)) * (H_ * D_);

    // ---- Q fragments (hoisted): col = h = c (clamped; masked at store); k = 32s+8p+j ----
    short8 qb[4];
    {
        const float* qrow = queries + (c < H_ ? c : 0) * D_;
        #pragma unroll
        for (int s = 0; s < 4; ++s) {
            const float4 a  = *(const float4*)(qrow + 32 * s + 8 * p);
            const float4 bq = *(const float4*)(qrow + 32 * s + 8 * p + 4);
            qb[s] = cvt8(a, bq);
        }
    }

    // ================= TILE 0 =================
    // loads (d = 32s + 8p + j)
    float4 f0 = *(const float4*)(xrow +  0), f1 = *(const float4*)(xrow +  4);
    float4 f2 = *(const float4*)(xrow + 32), f3 = *(const float4*)(xrow + 36);
    float4 f4 = *(const float4*)(xrow + 64), f5 = *(const float4*)(xrow + 68);
    float4 f6 = *(const float4*)(xrow + 96), f7 = *(const float4*)(xrow + 100);

    short8 xb0 = cvt8(f0, f1), xb1 = cvt8(f2, f3),
           xb2 = cvt8(f4, f5), xb3 = cvt8(f6, f7);

    // issue tile-1 loads NOW (fire-and-forget; land during tile-0 compute)
    const float* yrow = xrow + D_;
    float4 g0 = *(const float4*)(yrow +  0), g1 = *(const float4*)(yrow +  4);
    float4 g2 = *(const float4*)(yrow + 32), g3 = *(const float4*)(yrow + 36);
    float4 g4 = *(const float4*)(yrow + 64), g5 = *(const float4*)(yrow + 68);
    float4 g6 = *(const float4*)(yrow + 96), g7 = *(const float4*)(yrow + 100);

    // stage tile-0 to XL (swizzled)
    *(short8*)&XL[n * 136 + (( 0 + 8 * p) ^ swn)] = xb0;
    *(short8*)&XL[n * 136 + ((32 + 8 * p) ^ swn)] = xb1;
    *(short8*)&XL[n * 136 + ((64 + 8 * p) ^ swn)] = xb2;
    *(short8*)&XL[n * 136 + ((96 + 8 * p) ^ swn)] = xb3;

    const float scale = 0.0883883476483184f;  // 128^-0.5

    // QK^T + max-free softmax + WL/SM
    {
        f32x4 c1 = {0.f, 0.f, 0.f, 0.f};
        c1 = __builtin_amdgcn_mfma_f32_16x16x32_bf16(xb0, qb[0], c1, 0, 0, 0);
        c1 = __builtin_amdgcn_mfma_f32_16x16x32_bf16(xb1, qb[1], c1, 0, 0, 0);
        c1 = __builtin_amdgcn_mfma_f32_16x16x32_bf16(xb2, qb[2], c1, 0, 0, 0);
        c1 = __builtin_amdgcn_mfma_f32_16x16x32_bf16(xb3, qb[3], c1, 0, 0, 0);
        float e[4];
        #pragma unroll
        for (int r = 0; r < 4; ++r) e[r] = __expf(c1[r] * scale);
        float s_w = e[0] + e[1] + e[2] + e[3];
        s_w += __shfl_xor(s_w, 16);
        s_w += __shfl_xor(s_w, 32);
        if (l < 16) SM[c * 4 + w] = s_w;
        *(uint2*)&WL[c * 72 + 16 * w + 4 * p] =
            make_uint2(pk2(e[0], e[1]), pk2(e[2], e[3]));
    }
    lds_barrier();   // XL/WL/SM ready; tile-1 loads STAY in flight

    // PV tile 0
    {
        short8 a2[2];
        a2[0] = *(const short8*)&WL[c * 72 +  0 + 8 * p];
        a2[1] = *(const short8*)&WL[c * 72 + 32 + 8 * p];
        f32x4 o2[2];
        #pragma unroll
        for (int dti = 0; dti < 2; ++dti) {
            const int dt = 2 * w + dti;
            f32x4 acc = {0.f, 0.f, 0.f, 0.f};
            #pragma unroll
            for (int ks = 0; ks < 2; ++ks) {
                const int base = (32 * ks + 8 * p) * 136 + ((16 * dt + c) ^ (p << 4));
                short8 bf;
                #pragma unroll
                for (int jj = 0; jj < 8; ++jj)
                    bf[jj] = (short)XL[base + 136 * jj];
                acc = __builtin_amdgcn_mfma_f32_16x16x32_bf16(a2[ks], bf, acc, 0, 0, 0);
            }
            o2[dti] = acc;
        }
        float rz[4];
        #pragma unroll
        for (int r = 0; r < 4; ++r) {
            const float4 z4 = *(const float4*)&SM[(4 * p + r) * 4];
            rz[r] = 1.0f / (z4.x + z4.y + z4.z + z4.w);
        }
        #pragma unroll
        for (int dti = 0; dti < 2; ++dti) {
            const int d = 16 * (2 * w + dti) + c;
            #pragma unroll
            for (int r = 0; r < 4; ++r) {
                const int h = 4 * p + r;
                if (h < H_) obt[h * D_ + d] = o2[dti][r] * rz[r];
            }
        }
    }
    lds_barrier();   // all XL/WL/SM reads done -> safe to overwrite

    // ================= TILE 1 =================
    // cvt (compiler inserts the vmcnt waits on g* here — long since landed)
    xb0 = cvt8(g0, g1); xb1 = cvt8(g2, g3);
    xb2 = cvt8(g4, g5); xb3 = cvt8(g6, g7);

    *(short8*)&XL[n * 136 + (( 0 + 8 * p) ^ swn)] = xb0;
    *(short8*)&XL[n * 136 + ((32 + 8 * p) ^ swn)] = xb1;
    *(short8*)&XL[n * 136 + ((64 + 8 * p) ^ swn)] = xb2;
    *(short8*)&XL[n * 136 + ((96 + 8 * p) ^ swn)] = xb3;

    {
        f32x4 c1 = {0.f, 0.f, 0.f, 0.f};
        c1 = __builtin_amdgcn_mfma_f32_16x16x32_bf16(xb0, qb[0], c1, 0, 0, 0);
        c1 = __builtin_amdgcn_mfma_f32_16x16x32_bf16(xb1, qb[1], c1, 0, 0, 0);
        c1 = __builtin_amdgcn_mfma_f32_16x16x32_bf16(xb2, qb[2], c1, 0, 0, 0);
        c1 = __builtin_amdgcn_mfma_f32_16x16x32_bf16(xb3, qb[3], c1, 0, 0, 0);
        float e[4];
        #pragma unroll
        for (int r = 0; r < 4; ++r) e[r] = __expf(c1[r] * scale);
        float s_w = e[0] + e[1] + e[2] + e[3];
        s_w += __shfl_xor(s_w, 16);
        s_w += __shfl_xor(s_w, 32);
        if (l < 16) SM[c * 4 + w] = s_w;
        *(uint2*)&WL[c * 72 + 16 * w + 4 * p] =
            make_uint2(pk2(e[0], e[1]), pk2(e[2], e[3]));
    }
    lds_barrier();

    // PV tile 1
    {
        short8 a2[2];
        a2[0] = *(const short8*)&WL[c * 72 +  0 + 8 * p];
        a2[1] = *(const short8*)&WL[c * 72 + 32 + 8 * p];
        f32x4 o2[2];
        #pragma unroll
        for (int dti = 0; dti < 2; ++dti) {
            const int dt = 2 * w + dti;
            f32x4 acc = {0.f, 0.f, 0.f, 0.f};
            #pragma unroll
            for (int ks = 0; ks < 2; ++ks) {
                const int base = (32 * ks + 8 * p) * 136 + ((16 * dt + c) ^ (p << 4));
                short8 bf;
                #pragma unroll
                for (int jj = 0; jj < 8; ++jj)
                    bf[jj] = (short)XL[base + 136 * jj];
                acc = __builtin_amdgcn_mfma_f32_16x16x32_bf16(a2[ks], bf, acc, 0, 0, 0);
            }
            o2[dti] = acc;
        }
        float rz[4];
        #pragma unroll
        for (int r = 0; r < 4; ++r) {
            const float4 z4 = *(const float4*)&SM[(4 * p + r) * 4];
            rz[r] = 1.0f / (z4.x + z4.y + z4.z + z4.w);
        }
        float* obt1 = obt + H_ * D_;
        #pragma unroll
        for (int dti = 0; dti < 2; ++dti) {
            const int d = 16 * (2 * w + dti) + c;
            #pragma unroll
            for (int r = 0; r < 4; ++r) {
                const int h = 4 * p + r;
                if (h < H_) obt1[h * D_ + d] = o2[dti][r] * rz[r];
            }
        }
    }
}

extern "C" void kernel_launch(void* const* d_in, const int* in_sizes, int n_in,
                              void* d_out, int out_size, void* d_ws, size_t ws_size,
                              hipStream_t stream) {
    // d_in[0] = ego (B,T,D) -- unused by the reference computation
    const float* others  = (const float*)d_in[1];   // (B,N,T,D) f32
    const float* queries = (const float*)d_in[2];   // (H,D) f32
    float* out = (float*)d_out;                     // (B,T,H,D) f32

    dim3 grid(B_ * T_ / 2);
    dim3 block(256);
    MultiHeadPool_45226005627089_kernel<<<grid, block, 0, stream>>>(others, queries, out);
}

// Round 14
// 28.447 us; speedup vs baseline: 1.2400x; 1.0322x over previous
//
#include <hip/hip_runtime.h>
#include <hip/hip_bf16.h>

#define B_ 8
#define N_ 64
#define T_ 512
#define D_ 128
#define H_ 7
#define TPB 4   // tiles (t-values) per block; grid = 4096/TPB = 1024 = 4 blocks/CU

typedef __attribute__((ext_vector_type(8))) short short8;   // 8 bf16 (MFMA A/B frag)
typedef __attribute__((ext_vector_type(4))) float f32x4;    // MFMA C/D frag
typedef __attribute__((ext_vector_type(4))) int   iv4;

union BF2 { __hip_bfloat162 h2; unsigned u; };
__device__ __forceinline__ unsigned pk2(float a, float b) {  // v_cvt_pk_bf16_f32 (RNE)
    BF2 r; r.h2 = __float22bfloat162_rn(make_float2(a, b)); return r.u;
}
__device__ __forceinline__ short8 cvt8(const float4& a, const float4& b) {
    iv4 v = { (int)pk2(a.x, a.y), (int)pk2(a.z, a.w),
              (int)pk2(b.x, b.y), (int)pk2(b.z, b.w) };
    return __builtin_bit_cast(short8, v);
}

// Raw barrier that does NOT drain vmcnt: in-flight global loads survive it.
__device__ __forceinline__ void lds_barrier() {
    asm volatile("s_waitcnt lgkmcnt(0)" ::: "memory");
    asm volatile("s_barrier" ::: "memory");
}

// TPB=4 rolling-prefetch persistent blocks (R13 mechanism, deeper pipeline):
// single dispatch generation (1024 blocks = 4/CU); tile i+1's 16 dwordx4
// loads issue before tile i's compute and ride across lgkm-only barriers.
// Max-free softmax (logits ~ N(0,1)); per-h 1/Z post-PV.
// Frag layouts (m89-verified): A row=l&15,k=(l>>4)*8+j; B col=l&15,k same;
// C/D col=l&15, row=(l>>4)*4+reg.
__global__ __launch_bounds__(256, 4)
void MultiHeadPool_45226005627089_kernel(const float* __restrict__ others,
                                         const float* __restrict__ queries,
                                         float* __restrict__ out) {
    __shared__ __align__(16) ushort XL[N_ * 136];   // bf16 X, row pad 136, d-swizzled
    __shared__ __align__(16) ushort WL[16 * 72];    // bf16 unnormalized e[h][n]
    __shared__ __align__(16) float  SM[16 * 4];     // per-(h,wave) partial sum

    const int tid = threadIdx.x;
    const int w   = tid >> 6;        // wave 0..3
    const int l   = tid & 63;
    const int c   = l & 15;
    const int p   = l >> 4;

    const int blk = blockIdx.x;          // 1024 blocks; tiles t0 .. t0+3
    const int b   = blk >> 7;            // 128 blocks per batch
    const int t0  = (blk & 127) * TPB;

    const int    n    = 16 * w + c;
    const int    swn  = ((n >> 3) & 3) << 4;        // d-chunk XOR swizzle for XL
    const float* xrow = others + ((size_t)b * N_ * T_ + t0) * D_
                               + (size_t)n * (T_ * D_) + 8 * p;
    float* obt = out + ((size_t)(b * T_ + t0)) * (H_ * D_);

    // ---- Q fragments (hoisted): col = h = c (clamped; masked at store); k = 32s+8p+j ----
    short8 qb0, qb1, qb2, qb3;
    {
        const float* qrow = queries + (c < H_ ? c : 0) * D_ + 8 * p;
        qb0 = cvt8(*(const float4*)(qrow +  0), *(const float4*)(qrow +  4));
        qb1 = cvt8(*(const float4*)(qrow + 32), *(const float4*)(qrow + 36));
        qb2 = cvt8(*(const float4*)(qrow + 64), *(const float4*)(qrow + 68));
        qb3 = cvt8(*(const float4*)(qrow + 96), *(const float4*)(qrow + 100));
    }

    const float scale = 0.0883883476483184f;  // 128^-0.5

    // prologue: issue tile-0 loads
    float4 g0 = *(const float4*)(xrow +  0), g1 = *(const float4*)(xrow +  4);
    float4 g2 = *(const float4*)(xrow + 32), g3 = *(const float4*)(xrow + 36);
    float4 g4 = *(const float4*)(xrow + 64), g5 = *(const float4*)(xrow + 68);
    float4 g6 = *(const float4*)(xrow + 96), g7 = *(const float4*)(xrow + 100);

#define TILE_BODY(IT)                                                          \
    do {                                                                       \
        /* cvt current tile (waits on its loads) */                            \
        short8 xb0 = cvt8(g0, g1), xb1 = cvt8(g2, g3),                         \
               xb2 = cvt8(g4, g5), xb3 = cvt8(g6, g7);                         \
        /* issue next tile's loads (ride across the lgkm barriers below) */    \
        if ((IT) < TPB - 1) {                                                  \
            const float* yrow = xrow + ((IT) + 1) * D_;                        \
            g0 = *(const float4*)(yrow +  0); g1 = *(const float4*)(yrow +  4);\
            g2 = *(const float4*)(yrow + 32); g3 = *(const float4*)(yrow + 36);\
            g4 = *(const float4*)(yrow + 64); g5 = *(const float4*)(yrow + 68);\
            g6 = *(const float4*)(yrow + 96); g7 = *(const float4*)(yrow + 100);\
        }                                                                      \
        /* stage current tile to XL (swizzled) */                              \
        *(short8*)&XL[n * 136 + (( 0 + 8 * p) ^ swn)] = xb0;                   \
        *(short8*)&XL[n * 136 + ((32 + 8 * p) ^ swn)] = xb1;                   \
        *(short8*)&XL[n * 136 + ((64 + 8 * p) ^ swn)] = xb2;                   \
        *(short8*)&XL[n * 136 + ((96 + 8 * p) ^ swn)] = xb3;                   \
        /* QK^T + max-free softmax -> WL, SM */                                \
        {                                                                      \
            f32x4 c1 = {0.f, 0.f, 0.f, 0.f};                                   \
            c1 = __builtin_amdgcn_mfma_f32_16x16x32_bf16(xb0, qb0, c1, 0, 0, 0);\
            c1 = __builtin_amdgcn_mfma_f32_16x16x32_bf16(xb1, qb1, c1, 0, 0, 0);\
            c1 = __builtin_amdgcn_mfma_f32_16x16x32_bf16(xb2, qb2, c1, 0, 0, 0);\
            c1 = __builtin_amdgcn_mfma_f32_16x16x32_bf16(xb3, qb3, c1, 0, 0, 0);\
            float e0 = __expf(c1[0] * scale), e1 = __expf(c1[1] * scale);      \
            float e2 = __expf(c1[2] * scale), e3 = __expf(c1[3] * scale);      \
            float s_w = e0 + e1 + e2 + e3;                                     \
            s_w += __shfl_xor(s_w, 16);                                        \
            s_w += __shfl_xor(s_w, 32);                                        \
            if (l < 16) SM[c * 4 + w] = s_w;                                   \
            *(uint2*)&WL[c * 72 + 16 * w + 4 * p] =                            \
                make_uint2(pk2(e0, e1), pk2(e2, e3));                          \
        }                                                                      \
        lds_barrier();   /* XL/WL/SM ready; next-tile loads stay in flight */  \
        /* PV + normalize + store */                                           \
        {                                                                      \
            short8 a20 = *(const short8*)&WL[c * 72 +  0 + 8 * p];             \
            short8 a21 = *(const short8*)&WL[c * 72 + 32 + 8 * p];             \
            f32x4 o20, o21;                                                    \
            {                                                                  \
                const int dt = 2 * w;                                          \
                f32x4 acc = {0.f, 0.f, 0.f, 0.f};                              \
                const int b0 = (8 * p) * 136 + ((16 * dt + c) ^ (p << 4));     \
                short8 bf;                                                     \
                _Pragma("unroll")                                              \
                for (int jj = 0; jj < 8; ++jj) bf[jj] = (short)XL[b0 + 136 * jj];\
                acc = __builtin_amdgcn_mfma_f32_16x16x32_bf16(a20, bf, acc, 0, 0, 0);\
                const int b1 = (32 + 8 * p) * 136 + ((16 * dt + c) ^ (p << 4));\
                _Pragma("unroll")                                              \
                for (int jj = 0; jj < 8; ++jj) bf[jj] = (short)XL[b1 + 136 * jj];\
                acc = __builtin_amdgcn_mfma_f32_16x16x32_bf16(a21, bf, acc, 0, 0, 0);\
                o20 = acc;                                                     \
            }                                                                  \
            {                                                                  \
                const int dt = 2 * w + 1;                                      \
                f32x4 acc = {0.f, 0.f, 0.f, 0.f};                              \
                const int b0 = (8 * p) * 136 + ((16 * dt + c) ^ (p << 4));     \
                short8 bf;                                                     \
                _Pragma("unroll")                                              \
                for (int jj = 0; jj < 8; ++jj) bf[jj] = (short)XL[b0 + 136 * jj];\
                acc = __builtin_amdgcn_mfma_f32_16x16x32_bf16(a20, bf, acc, 0, 0, 0);\
                const int b1 = (32 + 8 * p) * 136 + ((16 * dt + c) ^ (p << 4));\
                _Pragma("unroll")                                              \
                for (int jj = 0; jj < 8; ++jj) bf[jj] = (short)XL[b1 + 136 * jj];\
                acc = __builtin_amdgcn_mfma_f32_16x16x32_bf16(a21, bf, acc, 0, 0, 0);\
                o21 = acc;                                                     \
            }                                                                  \
            float rz0, rz1, rz2, rz3;                                          \
            {                                                                  \
                const float4 z0 = *(const float4*)&SM[(4 * p + 0) * 4];        \
                const float4 z1 = *(const float4*)&SM[(4 * p + 1) * 4];        \
                const float4 z2 = *(const float4*)&SM[(4 * p + 2) * 4];        \
                const float4 z3 = *(const float4*)&SM[(4 * p + 3) * 4];        \
                rz0 = 1.0f / (z0.x + z0.y + z0.z + z0.w);                      \
                rz1 = 1.0f / (z1.x + z1.y + z1.z + z1.w);                      \
                rz2 = 1.0f / (z2.x + z2.y + z2.z + z2.w);                      \
                rz3 = 1.0f / (z3.x + z3.y + z3.z + z3.w);                      \
            }                                                                  \
            float* ob = obt + (IT) * (H_ * D_);                                \
            const int d0 = 16 * (2 * w) + c, d1 = d0 + 16;                     \
            if (4 * p + 0 < H_) { ob[(4*p+0) * D_ + d0] = o20[0] * rz0;        \
                                  ob[(4*p+0) * D_ + d1] = o21[0] * rz0; }      \
            if (4 * p + 1 < H_) { ob[(4*p+1) * D_ + d0] = o20[1] * rz1;        \
                                  ob[(4*p+1) * D_ + d1] = o21[1] * rz1; }      \
            if (4 * p + 2 < H_) { ob[(4*p+2) * D_ + d0] = o20[2] * rz2;        \
                                  ob[(4*p+2) * D_ + d1] = o21[2] * rz2; }      \
            if (4 * p + 3 < H_) { ob[(4*p+3) * D_ + d0] = o20[3] * rz3;        \
                                  ob[(4*p+3) * D_ + d1] = o21[3] * rz3; }      \
        }                                                                      \
        if ((IT) < TPB - 1) lds_barrier();  /* XL/WL/SM free for next tile */  \
    } while (0)

    TILE_BODY(0);
    TILE_BODY(1);
    TILE_BODY(2);
    TILE_BODY(3);
#undef TILE_BODY
}

extern "C" void kernel_launch(void* const* d_in, const int* in_sizes, int n_in,
                              void* d_out, int out_size, void* d_ws, size_t ws_size,
                              hipStream_t stream) {
    // d_in[0] = ego (B,T,D) -- unused by the reference computation
    const float* others  = (const float*)d_in[1];   // (B,N,T,D) f32
    const float* queries = (const float*)d_in[2];   // (H,D) f32
    float* out = (float*)d_out;                     // (B,T,H,D) f32

    dim3 grid(B_ * T_ / TPB);
    dim3 block(256);
    MultiHeadPool_45226005627089_kernel<<<grid, block, 0, stream>>>(others, queries, out);
}

// Round 15
// 28.215 us; speedup vs baseline: 1.2502x; 1.0082x over previous
//
#include <hip/hip_runtime.h>
#include <hip/hip_bf16.h>

#define B_ 8
#define N_ 64
#define T_ 512
#define D_ 128
#define H_ 7
#define TPB 4   // tiles (t-values) per block; grid = 4096/TPB = 1024 = 4 blocks/CU

typedef __attribute__((ext_vector_type(8))) short short8;   // 8 bf16 (MFMA A/B frag)
typedef __attribute__((ext_vector_type(4))) float f32x4;    // MFMA C/D frag
typedef __attribute__((ext_vector_type(4))) int   iv4;

union BF2 { __hip_bfloat162 h2; unsigned u; };
__device__ __forceinline__ unsigned pk2(float a, float b) {  // v_cvt_pk_bf16_f32 (RNE)
    BF2 r; r.h2 = __float22bfloat162_rn(make_float2(a, b)); return r.u;
}
__device__ __forceinline__ short8 cvt8(const float4& a, const float4& b) {
    iv4 v = { (int)pk2(a.x, a.y), (int)pk2(a.z, a.w),
              (int)pk2(b.x, b.y), (int)pk2(b.z, b.w) };
    return __builtin_bit_cast(short8, v);
}

// Raw barrier that does NOT drain vmcnt: in-flight global loads survive it.
__device__ __forceinline__ void lds_barrier() {
    asm volatile("s_waitcnt lgkmcnt(0)" ::: "memory");
    asm volatile("s_barrier" ::: "memory");
}

// R14 + ping-pong LDS buffers -> ONE barrier per tile (was 2).
// Safety: passing tile-i's barrier implies every wave finished tile-(i-1)'s PV
// (program order: PV(i-1) < stage(i) < barrier(i)), so stage(i+1) into the
// other buffer can never race a reader.
// Max-free softmax (logits ~ N(0,1)); per-h 1/Z post-PV.
// Frag layouts (m89-verified): A row=l&15,k=(l>>4)*8+j; B col=l&15,k same;
// C/D col=l&15, row=(l>>4)*4+reg.
__global__ __launch_bounds__(256, 4)
void MultiHeadPool_45226005627089_kernel(const float* __restrict__ others,
                                         const float* __restrict__ queries,
                                         float* __restrict__ out) {
    __shared__ __align__(16) ushort XL0[N_ * 136], XL1[N_ * 136]; // bf16 X, swizzled
    __shared__ __align__(16) ushort WL0[16 * 72],  WL1[16 * 72];  // bf16 e[h][n]
    __shared__ __align__(16) float  SM0[16 * 4],   SM1[16 * 4];   // (h,wave) partial sums

    const int tid = threadIdx.x;
    const int w   = tid >> 6;        // wave 0..3
    const int l   = tid & 63;
    const int c   = l & 15;
    const int p   = l >> 4;

    const int blk = blockIdx.x;          // 1024 blocks; tiles t0 .. t0+3
    const int b   = blk >> 7;            // 128 blocks per batch
    const int t0  = (blk & 127) * TPB;

    const int    n    = 16 * w + c;
    const int    swn  = ((n >> 3) & 3) << 4;        // d-chunk XOR swizzle for XL
    const float* xrow = others + ((size_t)b * N_ * T_ + t0) * D_
                               + (size_t)n * (T_ * D_) + 8 * p;
    float* obt = out + ((size_t)(b * T_ + t0)) * (H_ * D_);

    // ---- Q fragments (hoisted): col = h = c (clamped; masked at store); k = 32s+8p+j ----
    short8 qb0, qb1, qb2, qb3;
    {
        const float* qrow = queries + (c < H_ ? c : 0) * D_ + 8 * p;
        qb0 = cvt8(*(const float4*)(qrow +  0), *(const float4*)(qrow +  4));
        qb1 = cvt8(*(const float4*)(qrow + 32), *(const float4*)(qrow + 36));
        qb2 = cvt8(*(const float4*)(qrow + 64), *(const float4*)(qrow + 68));
        qb3 = cvt8(*(const float4*)(qrow + 96), *(const float4*)(qrow + 100));
    }

    const float scale = 0.0883883476483184f;  // 128^-0.5

    // prologue: issue tile-0 loads
    float4 g0 = *(const float4*)(xrow +  0), g1 = *(const float4*)(xrow +  4);
    float4 g2 = *(const float4*)(xrow + 32), g3 = *(const float4*)(xrow + 36);
    float4 g4 = *(const float4*)(xrow + 64), g5 = *(const float4*)(xrow + 68);
    float4 g6 = *(const float4*)(xrow + 96), g7 = *(const float4*)(xrow + 100);

#define TILE_BODY(IT, XL, WL, SM)                                              \
    do {                                                                       \
        short8 xb0 = cvt8(g0, g1), xb1 = cvt8(g2, g3),                         \
               xb2 = cvt8(g4, g5), xb3 = cvt8(g6, g7);                         \
        if ((IT) < TPB - 1) {                                                  \
            const float* yrow = xrow + ((IT) + 1) * D_;                        \
            g0 = *(const float4*)(yrow +  0); g1 = *(const float4*)(yrow +  4);\
            g2 = *(const float4*)(yrow + 32); g3 = *(const float4*)(yrow + 36);\
            g4 = *(const float4*)(yrow + 64); g5 = *(const float4*)(yrow + 68);\
            g6 = *(const float4*)(yrow + 96); g7 = *(const float4*)(yrow + 100);\
        }                                                                      \
        *(short8*)&XL[n * 136 + (( 0 + 8 * p) ^ swn)] = xb0;                   \
        *(short8*)&XL[n * 136 + ((32 + 8 * p) ^ swn)] = xb1;                   \
        *(short8*)&XL[n * 136 + ((64 + 8 * p) ^ swn)] = xb2;                   \
        *(short8*)&XL[n * 136 + ((96 + 8 * p) ^ swn)] = xb3;                   \
        {                                                                      \
            f32x4 c1 = {0.f, 0.f, 0.f, 0.f};                                   \
            c1 = __builtin_amdgcn_mfma_f32_16x16x32_bf16(xb0, qb0, c1, 0, 0, 0);\
            c1 = __builtin_amdgcn_mfma_f32_16x16x32_bf16(xb1, qb1, c1, 0, 0, 0);\
            c1 = __builtin_amdgcn_mfma_f32_16x16x32_bf16(xb2, qb2, c1, 0, 0, 0);\
            c1 = __builtin_amdgcn_mfma_f32_16x16x32_bf16(xb3, qb3, c1, 0, 0, 0);\
            float e0 = __expf(c1[0] * scale), e1 = __expf(c1[1] * scale);      \
            float e2 = __expf(c1[2] * scale), e3 = __expf(c1[3] * scale);      \
            float s_w = e0 + e1 + e2 + e3;                                     \
            s_w += __shfl_xor(s_w, 16);                                        \
            s_w += __shfl_xor(s_w, 32);                                        \
            if (l < 16) SM[c * 4 + w] = s_w;                                   \
            *(uint2*)&WL[c * 72 + 16 * w + 4 * p] =                            \
                make_uint2(pk2(e0, e1), pk2(e2, e3));                          \
        }                                                                      \
        lds_barrier();   /* buf[cur] ready; in-flight loads survive */         \
        {                                                                      \
            short8 a20 = *(const short8*)&WL[c * 72 +  0 + 8 * p];             \
            short8 a21 = *(const short8*)&WL[c * 72 + 32 + 8 * p];             \
            f32x4 o20, o21;                                                    \
            {                                                                  \
                const int dt = 2 * w;                                          \
                f32x4 acc = {0.f, 0.f, 0.f, 0.f};                              \
                const int b0 = (8 * p) * 136 + ((16 * dt + c) ^ (p << 4));     \
                short8 bf;                                                     \
                _Pragma("unroll")                                              \
                for (int jj = 0; jj < 8; ++jj) bf[jj] = (short)XL[b0 + 136 * jj];\
                acc = __builtin_amdgcn_mfma_f32_16x16x32_bf16(a20, bf, acc, 0, 0, 0);\
                const int b1 = (32 + 8 * p) * 136 + ((16 * dt + c) ^ (p << 4));\
                _Pragma("unroll")                                              \
                for (int jj = 0; jj < 8; ++jj) bf[jj] = (short)XL[b1 + 136 * jj];\
                acc = __builtin_amdgcn_mfma_f32_16x16x32_bf16(a21, bf, acc, 0, 0, 0);\
                o20 = acc;                                                     \
            }                                                                  \
            {                                                                  \
                const int dt = 2 * w + 1;                                      \
                f32x4 acc = {0.f, 0.f, 0.f, 0.f};                              \
                const int b0 = (8 * p) * 136 + ((16 * dt + c) ^ (p << 4));     \
                short8 bf;                                                     \
                _Pragma("unroll")                                              \
                for (int jj = 0; jj < 8; ++jj) bf[jj] = (short)XL[b0 + 136 * jj];\
                acc = __builtin_amdgcn_mfma_f32_16x16x32_bf16(a20, bf, acc, 0, 0, 0);\
                const int b1 = (32 + 8 * p) * 136 + ((16 * dt + c) ^ (p << 4));\
                _Pragma("unroll")                                              \
                for (int jj = 0; jj < 8; ++jj) bf[jj] = (short)XL[b1 + 136 * jj];\
                acc = __builtin_amdgcn_mfma_f32_16x16x32_bf16(a21, bf, acc, 0, 0, 0);\
                o21 = acc;                                                     \
            }                                                                  \
            float rz0, rz1, rz2, rz3;                                          \
            {                                                                  \
                const float4 z0 = *(const float4*)&SM[(4 * p + 0) * 4];        \
                const float4 z1 = *(const float4*)&SM[(4 * p + 1) * 4];        \
                const float4 z2 = *(const float4*)&SM[(4 * p + 2) * 4];        \
                const float4 z3 = *(const float4*)&SM[(4 * p + 3) * 4];        \
                rz0 = 1.0f / (z0.x + z0.y + z0.z + z0.w);                      \
                rz1 = 1.0f / (z1.x + z1.y + z1.z + z1.w);                      \
                rz2 = 1.0f / (z2.x + z2.y + z2.z + z2.w);                      \
                rz3 = 1.0f / (z3.x + z3.y + z3.z + z3.w);                      \
            }                                                                  \
            float* ob = obt + (IT) * (H_ * D_);                                \
            const int d0 = 16 * (2 * w) + c, d1 = d0 + 16;                     \
            if (4 * p + 0 < H_) { ob[(4*p+0) * D_ + d0] = o20[0] * rz0;        \
                                  ob[(4*p+0) * D_ + d1] = o21[0] * rz0; }      \
            if (4 * p + 1 < H_) { ob[(4*p+1) * D_ + d0] = o20[1] * rz1;        \
                                  ob[(4*p+1) * D_ + d1] = o21[1] * rz1; }      \
            if (4 * p + 2 < H_) { ob[(4*p+2) * D_ + d0] = o20[2] * rz2;        \
                                  ob[(4*p+2) * D_ + d1] = o21[2] * rz2; }      \
            if (4 * p + 3 < H_) { ob[(4*p+3) * D_ + d0] = o20[3] * rz3;        \
                                  ob[(4*p+3) * D_ + d1] = o21[3] * rz3; }      \
        }                                                                      \
        /* no second barrier: next tile stages into the OTHER buffer */        \
    } while (0)

    TILE_BODY(0, XL0, WL0, SM0);
    TILE_BODY(1, XL1, WL1, SM1);
    TILE_BODY(2, XL0, WL0, SM0);
    TILE_BODY(3, XL1, WL1, SM1);
#undef TILE_BODY
}

extern "C" void kernel_launch(void* const* d_in, const int* in_sizes, int n_in,
                              void* d_out, int out_size, void* d_ws, size_t ws_size,
                              hipStream_t stream) {
    // d_in[0] = ego (B,T,D) -- unused by the reference computation
    const float* others  = (const float*)d_in[1];   // (B,N,T,D) f32
    const float* queries = (const float*)d_in[2];   // (H,D) f32
    float* out = (float*)d_out;                     // (B,T,H,D) f32

    dim3 grid(B_ * T_ / TPB);
    dim3 block(256);
    MultiHeadPool_45226005627089_kernel<<<grid, block, 0, stream>>>(others, queries, out);
}